// Round 9
// baseline (3726.590 us; speedup 1.0000x reference)
//
#include <hip/hip_runtime.h>

#define NLAT  256
#define NLON  512
#define LMAXX 128
#define MMAXX 128
#define NV    64
#define NBTE  4   // B*T*E = 2*2*1

// round-to-nearest-even float -> bf16
__device__ __forceinline__ unsigned int f2bf(float x) {
    union { float f; unsigned int u; } a; a.f = x;
    return (a.u + 0x7fffu + ((a.u >> 16) & 1u)) >> 16;
}

// ---------------------------------------------------------------------------
// PROBE DFT (trusted, r7): one thread per (row, m, v), direct sincosf.
// F layout: [bte][mi][lat][2v+comp] fp32.
// ---------------------------------------------------------------------------
__global__ __launch_bounds__(64) void dft_probe(const float* __restrict__ data,
                                                float* __restrict__ F,
                                                int m_base, int mch) {
    const int row = blockIdx.x;         // bte*NLAT + lat
    const int mi  = blockIdx.y;
    const int m   = m_base + mi;
    const int v   = threadIdx.x;        // 0..63
    const float* __restrict__ X = data + (size_t)row * (NLON * NV) + v;

    float re = 0.f, im = 0.f;
    for (int n = 0; n < NLON; ++n) {
        float s, c;
        sincosf((-6.28318530717958647692f / NLON) * (float)(m * n), &s, &c);
        const float x = X[(size_t)n * NV];
        re = fmaf(c, x, re);
        im = fmaf(s, x, im);
    }

    const int bte = row >> 8;
    const int lat = row & (NLAT - 1);
    float* dp = F + ((size_t)(bte * mch + mi) * NLAT + lat) * (NV * 2);
    dp[2 * v]     = re;
    dp[2 * v + 1] = im;
}

// ---------------------------------------------------------------------------
// Contraction (trusted values, r5/r7). One thread per output complex element.
// Positions: [b,t,e,l,m,v] (r3). WITHIN-PAIR HYPOTHESIS H_swap: (im, re).
//   flat: ((bte*128+l)*128+m)*128 + 2v + {0:im, 1:re}
// ---------------------------------------------------------------------------
__global__ __launch_bounds__(256) void contract_simple(const float* __restrict__ F,
                                                       const float* __restrict__ leg,
                                                       const float* __restrict__ qw,
                                                       unsigned short* __restrict__ out,
                                                       int m_base, int mch, int total) {
    const int gid = blockIdx.x * 256 + threadIdx.x;
    if (gid >= total) return;
    const int v   = gid & (NV - 1);
    int r         = gid >> 6;
    const int mi  = r % mch;  r /= mch;
    const int l   = r & (LMAXX - 1);
    const int bte = r >> 7;
    const int m   = m_base + mi;

    const float* __restrict__ lp = leg + ((size_t)l * MMAXX + m) * NLAT;
    const float* __restrict__ fp = F + (size_t)(bte * mch + mi) * (NLAT * NV * 2) + 2 * v;

    float re = 0.f, im = 0.f;
    #pragma unroll 4
    for (int k = 0; k < NLAT; ++k) {
        const float w = lp[k] * qw[k];
        re = fmaf(w, fp[(size_t)k * (NV * 2)],     re);
        im = fmaf(w, fp[(size_t)k * (NV * 2) + 1], im);
    }

    // H_swap: im first, then re
    const size_t base = ((size_t)(bte * LMAXX + l) * MMAXX + m) * (NV * 2) + 2 * v;
    out[base]     = (unsigned short)f2bf(im);
    out[base + 1] = (unsigned short)f2bf(re);
}

extern "C" void kernel_launch(void* const* d_in, const int* in_sizes, int n_in,
                              void* d_out, int out_size, void* d_ws, size_t ws_size,
                              hipStream_t stream) {
    const float* data = (const float*)d_in[0];    // [4][256][512][64] fp32
    const float* leg  = (const float*)d_in[1];    // [128][128][256] fp32
    const float* qw   = (const float*)d_in[2];    // [256] fp32
    unsigned short* out = (unsigned short*)d_out; // bf16 [4][128][128][64][im,re]
    float* F   = (float*)d_ws;

    // per-m footprint of F: 4 bte * 256 k * 128 c * 4 B = 512 KB
    const size_t per_m = (size_t)NBTE * NLAT * NV * 2 * sizeof(float);
    int mch = MMAXX;
    while (mch > 8 && per_m * (size_t)mch > ws_size) mch >>= 1;

    const int nch = MMAXX / mch;
    for (int c = 0; c < nch; ++c) {
        const int mb = c * mch;
        dft_probe<<<dim3(NBTE * NLAT, mch), 64, 0, stream>>>(data, F, mb, mch);
        const int total = NBTE * LMAXX * mch * NV;
        contract_simple<<<dim3((total + 255) / 256), 256, 0, stream>>>(F, leg, qw, out, mb, mch, total);
    }
}

// Round 10
// 278.833 us; speedup vs baseline: 13.3650x; 13.3650x over previous
//
#include <hip/hip_runtime.h>

#define NLAT  256
#define NLON  512
#define LMAXX 128
#define MMAXX 128
#define NV    64
#define NBTE  4   // B*T*E = 2*2*1

// round-to-nearest-even float -> bf16
__device__ __forceinline__ unsigned int f2bf(float x) {
    union { float f; unsigned int u; } a; a.f = x;
    return (a.u + 0x7fffu + ((a.u >> 16) & 1u)) >> 16;
}

// ---------------------------------------------------------------------------
// Kernel A: direct DFT over longitude for an m-chunk (r3-verified values).
// Row (bte, lat): F[mi][v] = sum_n X[n][v] * exp(-2*pi*i*(m_base+mi)*n/512).
// F layout: [bte][mi][k=lat][v*2+comp] fp32 (comp0=re), in d_ws.
// Block 256: thread owns MPT m x 8 v. mg = t>>3, vg = t&7.
// ---------------------------------------------------------------------------
template<int MPT>
__global__ __launch_bounds__(256) void dft_lon(const float* __restrict__ data,
                                               float* __restrict__ F,
                                               int m_base, int mch) {
    __shared__ float2 tw[NLON];        // 4 KB twiddle: (cos, -sin)
    __shared__ float  xs[64 * NV];     // 16 KB chunk [n_local][v]
    const int row = blockIdx.x;        // bte*NLAT + lat
    const int t   = threadIdx.x;
    const float* __restrict__ X = data + (size_t)row * (NLON * NV);

    for (int i = t; i < NLON; i += 256) {
        float s, c;
        sincosf((6.28318530717958647692f / NLON) * (float)i, &s, &c);
        tw[i] = make_float2(c, -s);
    }

    const int mg = t >> 3;             // 0..31
    const int vg = t & 7;              // 0..7
    const int m0 = m_base + mg * MPT;

    float ar[MPT][8], ai[MPT][8];
    #pragma unroll
    for (int j = 0; j < MPT; ++j)
        #pragma unroll
        for (int v = 0; v < 8; ++v) { ar[j][v] = 0.f; ai[j][v] = 0.f; }

    int idx[MPT];
    #pragma unroll
    for (int j = 0; j < MPT; ++j) idx[j] = 0;

    for (int chunk = 0; chunk < NLON / 64; ++chunk) {
        __syncthreads();
        const float4* src = (const float4*)(X + (size_t)chunk * 64 * NV);
        float4*       dst = (float4*)xs;
        #pragma unroll
        for (int j = 0; j < 4; ++j) dst[t + j * 256] = src[t + j * 256];
        __syncthreads();
        for (int n = 0; n < 64; ++n) {
            const float4 x0 = *(const float4*)&xs[n * NV + vg * 8];
            const float4 x1 = *(const float4*)&xs[n * NV + vg * 8 + 4];
            const float xv[8] = {x0.x, x0.y, x0.z, x0.w, x1.x, x1.y, x1.z, x1.w};
            #pragma unroll
            for (int j = 0; j < MPT; ++j) {
                const float2 w = tw[idx[j]];
                idx[j] = (idx[j] + m0 + j) & (NLON - 1);
                #pragma unroll
                for (int v = 0; v < 8; ++v) {
                    ar[j][v] = fmaf(w.x, xv[v], ar[j][v]);
                    ai[j][v] = fmaf(w.y, xv[v], ai[j][v]);
                }
            }
        }
    }

    const int bte = row >> 8;
    const int lat = row & (NLAT - 1);
    #pragma unroll
    for (int j = 0; j < MPT; ++j) {
        const int mi = mg * MPT + j;
        if (mi < mch) {
            float* dp = F + (((size_t)(bte * mch + mi) * NLAT + lat) * (NV * 2)) + vg * 16;
            ((float4*)dp)[0] = make_float4(ar[j][0], ai[j][0], ar[j][1], ai[j][1]);
            ((float4*)dp)[1] = make_float4(ar[j][2], ai[j][2], ar[j][3], ai[j][3]);
            ((float4*)dp)[2] = make_float4(ar[j][4], ai[j][4], ar[j][5], ai[j][5]);
            ((float4*)dp)[3] = make_float4(ar[j][6], ai[j][6], ar[j][7], ai[j][7]);
        }
    }
}

// ---------------------------------------------------------------------------
// Kernel B: out[bte][l][m][v][(im,re)] = sum_k leg[l][m][k]*qw[k]*F[bte][mi][k][c]
// grid (mch, NBTE), block 256: 8 l x 8 c (= 4 v) per thread. bf16 output.
// VERIFIED output layout: positions [b,t,e,l,m,v], pair order (im, re).
// ---------------------------------------------------------------------------
__global__ __launch_bounds__(256) void leg_contract(const float* __restrict__ F,
                                                    const float* __restrict__ leg,
                                                    const float* __restrict__ qw,
                                                    unsigned short* __restrict__ out,
                                                    int m_base, int mch) {
    __shared__ float As[16 * 128];     // [kk][l]
    __shared__ float Fs[16 * 128];     // [kk][c] de-interleaved
    __shared__ float qs[NLAT];
    const int mi  = blockIdx.x;
    const int m   = m_base + mi;
    const int bte = blockIdx.y;
    const int t   = threadIdx.x;
    qs[t] = qw[t];

    const int cg = t & 15;             // c = cg*8 .. cg*8+7  (v = cg*4 .. cg*4+3)
    const int lq = t >> 4;             // l = lq*8 .. lq*8+7
    const int la = t >> 1;             // A-load: l row
    const int kh = (t & 1) * 8;        // A-load: k offset within 16-chunk

    const float4* Fb4 = (const float4*)(F + (size_t)(bte * mch + mi) * (NLAT * NV * 2));
    float4* As4 = (float4*)As;
    float4* Fs4 = (float4*)Fs;

    float acc[8][8];
    #pragma unroll
    for (int i = 0; i < 8; ++i)
        #pragma unroll
        for (int j = 0; j < 8; ++j) acc[i][j] = 0.f;

    for (int k0 = 0; k0 < NLAT; k0 += 16) {
        __syncthreads();
        {   // A: As[kk][l] = leg[la][m][k0+kk] * qw[k0+kk]
            const float* lp = leg + ((size_t)la * MMAXX + m) * NLAT + k0 + kh;
            const float4 p0 = *(const float4*)lp;
            const float4 p1 = *(const float4*)(lp + 4);
            const float pv[8] = {p0.x, p0.y, p0.z, p0.w, p1.x, p1.y, p1.z, p1.w};
            #pragma unroll
            for (int j = 0; j < 8; ++j)
                As[(kh + j) * 128 + la] = pv[j] * qs[k0 + kh + j];
        }
        #pragma unroll
        for (int j = 0; j < 2; ++j) {  // F: de-interleaved stage
            const int g  = t + j * 256;          // float4 index in 16x128 chunk
            const int kk = g >> 5;
            const int cc = g & 31;
            Fs4[kk * 32 + (((cc & 1) << 4) | (cc >> 1))] = Fb4[k0 * 32 + g];
        }
        __syncthreads();
        #pragma unroll 4
        for (int kk = 0; kk < 16; ++kk) {
            const float4 a0 = As4[kk * 32 + lq * 2];
            const float4 a1 = As4[kk * 32 + lq * 2 + 1];
            const float4 f0 = Fs4[kk * 32 + cg];
            const float4 f1 = Fs4[kk * 32 + 16 + cg];
            const float av[8] = {a0.x, a0.y, a0.z, a0.w, a1.x, a1.y, a1.z, a1.w};
            const float fv[8] = {f0.x, f0.y, f0.z, f0.w, f1.x, f1.y, f1.z, f1.w};
            #pragma unroll
            for (int i = 0; i < 8; ++i)
                #pragma unroll
                for (int j = 0; j < 8; ++j)
                    acc[i][j] = fmaf(av[i], fv[j], acc[i][j]);
        }
    }

    // Epilogue: acc[i][j] is (l=lq*8+i, c=cg*8+j), c=2v+comp with comp0=re.
    // Output pair order is (im, re): low16 of each u32 = im (acc odd), hi = re.
    #pragma unroll
    for (int i = 0; i < 8; ++i) {
        const int l = lq * 8 + i;
        unsigned short* dp = out + ((size_t)(bte * LMAXX + l) * MMAXX + m) * (NV * 2) + cg * 8;
        uint4 pk;
        pk.x = f2bf(acc[i][1]) | (f2bf(acc[i][0]) << 16);
        pk.y = f2bf(acc[i][3]) | (f2bf(acc[i][2]) << 16);
        pk.z = f2bf(acc[i][5]) | (f2bf(acc[i][4]) << 16);
        pk.w = f2bf(acc[i][7]) | (f2bf(acc[i][6]) << 16);
        *(uint4*)dp = pk;
    }
}

extern "C" void kernel_launch(void* const* d_in, const int* in_sizes, int n_in,
                              void* d_out, int out_size, void* d_ws, size_t ws_size,
                              hipStream_t stream) {
    const float* data = (const float*)d_in[0];    // [4][256][512][64] fp32
    const float* leg  = (const float*)d_in[1];    // [128][128][256] fp32
    const float* qw   = (const float*)d_in[2];    // [256] fp32
    unsigned short* out = (unsigned short*)d_out; // bf16 [4][128][128][64][(im,re)]
    float* F   = (float*)d_ws;

    // per-m footprint of F: 4 bte * 256 k * 128 c * 4 B = 512 KB
    const size_t per_m = (size_t)NBTE * NLAT * NV * 2 * sizeof(float);
    int mch = MMAXX;
    while (mch > 8 && per_m * (size_t)mch > ws_size) mch >>= 1;

    const int nch = MMAXX / mch;
    for (int c = 0; c < nch; ++c) {
        const int mb = c * mch;
        if (mch >= 128)
            dft_lon<4><<<dim3(NBTE * NLAT), 256, 0, stream>>>(data, F, mb, mch);
        else if (mch == 64)
            dft_lon<2><<<dim3(NBTE * NLAT), 256, 0, stream>>>(data, F, mb, mch);
        else
            dft_lon<1><<<dim3(NBTE * NLAT), 256, 0, stream>>>(data, F, mb, mch);
        leg_contract<<<dim3(mch, NBTE), 256, 0, stream>>>(F, leg, qw, out, mb, mch);
    }
}

// Round 11
// 159.471 us; speedup vs baseline: 23.3684x; 1.7485x over previous
//
#include <hip/hip_runtime.h>

#define NLAT  256
#define NLON  512
#define LMAXX 128
#define MMAXX 128
#define NV    64
#define NBTE  4   // B*T*E = 2*2*1

typedef __attribute__((ext_vector_type(8))) short bf16x8;
typedef __attribute__((ext_vector_type(4))) short bf16x4;
typedef __attribute__((ext_vector_type(4))) float f32x4;

// round-to-nearest-even float -> bf16
__device__ __forceinline__ unsigned int f2bf(float x) {
    union { float f; unsigned int u; } a; a.f = x;
    return (a.u + 0x7fffu + ((a.u >> 16) & 1u)) >> 16;
}

// ---------------------------------------------------------------------------
// init_tsw: twiddle matrix T[256][512] bf16, pre-swizzled into MFMA A-fragment
// order.  T[row][n]: row<128 -> cos(2*pi*row*n/512) (re), row>=128 -> -sin (im).
// Fragment layout (mfma_f32_16x16x32_bf16 A): lane holds A[row=l&15][k=(l>>4)*8+i].
// Flat: tsw[((ks*16 + mt)*64 + l)*8 + i] = T[mt*16+(l&15)][ks*32+(l>>4)*8+i]
// ---------------------------------------------------------------------------
__global__ __launch_bounds__(256) void init_tsw(unsigned short* __restrict__ tsw) {
    const int gid = blockIdx.x * 256 + threadIdx.x;   // 131072 total
    const int i  = gid & 7;
    const int l  = (gid >> 3) & 63;
    const int mt = (gid >> 9) & 15;
    const int ks = gid >> 13;
    const int row = mt * 16 + (l & 15);
    const int n   = ks * 32 + (l >> 4) * 8 + i;
    const int m   = row & 127;
    float s, c;
    sincosf((6.28318530717958647692f / NLON) * (float)((m * n) & (NLON - 1)), &s, &c);
    const float val = (row < 128) ? c : -s;
    tsw[gid] = (unsigned short)f2bf(val);
}

// ---------------------------------------------------------------------------
// dft_mfma: F[bte][m][lat][c][v] (PLANAR fp32: c=0 re, c=1 im)
//   = sum_n T[2-plane m-rows][n] * X[bte][lat][n][v]  via bf16 MFMA.
// Block: 2 lat-rows, 4 waves = 4 v-quarters; each wave: full M=256, N=16, 2 rows.
// ---------------------------------------------------------------------------
__global__ __launch_bounds__(256) void dft_mfma(const float* __restrict__ data,
                                                const unsigned short* __restrict__ tsw,
                                                float* __restrict__ F) {
    __shared__ unsigned short xs[2][64][136];   // [row][v][n-chunk+pad] bf16, 34.8 KB
    const int t = threadIdx.x;
    const int l = t & 63;
    const int q = t >> 6;              // wave = v quarter
    const int p = blockIdx.x;          // lat-row pair

    f32x4 acc[2][16];
    #pragma unroll
    for (int r = 0; r < 2; ++r)
        #pragma unroll
        for (int mt = 0; mt < 16; ++mt) acc[r][mt] = (f32x4){0.f, 0.f, 0.f, 0.f};

    const int rr = t >> 7;             // staging: row
    const int nh = (t >> 6) & 1;       // staging: n half
    const int vv = t & 63;             // staging: v

    for (int ch = 0; ch < 4; ++ch) {   // 128-n chunks
        __syncthreads();
        {   // stage X: fp32 -> bf16, transposed to [v][n]
            const float* Xp = data + ((size_t)(p * 2 + rr) * NLON + ch * 128 + nh * 64) * NV + vv;
            #pragma unroll
            for (int g = 0; g < 16; ++g) {
                bf16x4 pk;
                pk.x = (short)f2bf(Xp[(g * 4 + 0) * NV]);
                pk.y = (short)f2bf(Xp[(g * 4 + 1) * NV]);
                pk.z = (short)f2bf(Xp[(g * 4 + 2) * NV]);
                pk.w = (short)f2bf(Xp[(g * 4 + 3) * NV]);
                *(bf16x4*)&xs[rr][vv][nh * 64 + g * 4] = pk;
            }
        }
        __syncthreads();
        #pragma unroll
        for (int ks = 0; ks < 4; ++ks) {   // k32 steps
            const bf16x8 b0 = *(const bf16x8*)&xs[0][q * 16 + (l & 15)][ks * 32 + (l >> 4) * 8];
            const bf16x8 b1 = *(const bf16x8*)&xs[1][q * 16 + (l & 15)][ks * 32 + (l >> 4) * 8];
            const unsigned short* ap = tsw + ((size_t)(ch * 4 + ks) * 16) * 512 + l * 8;
            #pragma unroll
            for (int mt = 0; mt < 16; ++mt) {
                const bf16x8 a = *(const bf16x8*)(ap + mt * 512);
                acc[0][mt] = __builtin_amdgcn_mfma_f32_16x16x32_bf16(a, b0, acc[0][mt], 0, 0, 0);
                acc[1][mt] = __builtin_amdgcn_mfma_f32_16x16x32_bf16(a, b1, acc[1][mt], 0, 0, 0);
            }
        }
    }

    // epilogue: D[row=mt*16+(l>>4)*4+j][col=v] -> F planar
    const int v  = q * 16 + (l & 15);
    const int g4 = (l >> 4) * 4;
    #pragma unroll
    for (int r = 0; r < 2; ++r) {
        const int row = p * 2 + r;
        const int bte = row >> 8, lat = row & (NLAT - 1);
        #pragma unroll
        for (int mt = 0; mt < 16; ++mt) {
            const int cpl = mt >> 3;              // 0 = re, 1 = im
            #pragma unroll
            for (int j = 0; j < 4; ++j) {
                const int m = (mt * 16 + g4 + j) & 127;
                F[((size_t)(bte * MMAXX + m) * NLAT + lat) * (NV * 2) + cpl * 64 + v] = acc[r][mt][j];
            }
        }
    }
}

// ---------------------------------------------------------------------------
// Fallback fp32 DFT (only if ws too small for full-m F) — planar F epilogue.
// ---------------------------------------------------------------------------
template<int MPT>
__global__ __launch_bounds__(256) void dft_lon(const float* __restrict__ data,
                                               float* __restrict__ F,
                                               int m_base, int mch) {
    __shared__ float2 tw[NLON];
    __shared__ float  xs[64 * NV];
    const int row = blockIdx.x;
    const int t   = threadIdx.x;
    const float* __restrict__ X = data + (size_t)row * (NLON * NV);

    for (int i = t; i < NLON; i += 256) {
        float s, c;
        sincosf((6.28318530717958647692f / NLON) * (float)i, &s, &c);
        tw[i] = make_float2(c, -s);
    }
    const int mg = t >> 3, vg = t & 7;
    const int m0 = m_base + mg * MPT;

    float ar[MPT][8], ai[MPT][8];
    #pragma unroll
    for (int j = 0; j < MPT; ++j)
        #pragma unroll
        for (int v = 0; v < 8; ++v) { ar[j][v] = 0.f; ai[j][v] = 0.f; }
    int idx[MPT];
    #pragma unroll
    for (int j = 0; j < MPT; ++j) idx[j] = 0;

    for (int chunk = 0; chunk < NLON / 64; ++chunk) {
        __syncthreads();
        const float4* src = (const float4*)(X + (size_t)chunk * 64 * NV);
        float4*       dst = (float4*)xs;
        #pragma unroll
        for (int j = 0; j < 4; ++j) dst[t + j * 256] = src[t + j * 256];
        __syncthreads();
        for (int n = 0; n < 64; ++n) {
            const float4 x0 = *(const float4*)&xs[n * NV + vg * 8];
            const float4 x1 = *(const float4*)&xs[n * NV + vg * 8 + 4];
            const float xv[8] = {x0.x, x0.y, x0.z, x0.w, x1.x, x1.y, x1.z, x1.w};
            #pragma unroll
            for (int j = 0; j < MPT; ++j) {
                const float2 w = tw[idx[j]];
                idx[j] = (idx[j] + m0 + j) & (NLON - 1);
                #pragma unroll
                for (int v = 0; v < 8; ++v) {
                    ar[j][v] = fmaf(w.x, xv[v], ar[j][v]);
                    ai[j][v] = fmaf(w.y, xv[v], ai[j][v]);
                }
            }
        }
    }
    const int bte = row >> 8, lat = row & (NLAT - 1);
    #pragma unroll
    for (int j = 0; j < MPT; ++j) {
        const int mi = mg * MPT + j;
        if (mi < mch) {
            float* dp = F + ((size_t)(bte * mch + mi) * NLAT + lat) * (NV * 2);
            *(float4*)(dp + vg * 8)          = make_float4(ar[j][0], ar[j][1], ar[j][2], ar[j][3]);
            *(float4*)(dp + vg * 8 + 4)      = make_float4(ar[j][4], ar[j][5], ar[j][6], ar[j][7]);
            *(float4*)(dp + 64 + vg * 8)     = make_float4(ai[j][0], ai[j][1], ai[j][2], ai[j][3]);
            *(float4*)(dp + 64 + vg * 8 + 4) = make_float4(ai[j][4], ai[j][5], ai[j][6], ai[j][7]);
        }
    }
}

// ---------------------------------------------------------------------------
// leg_contract: out[bte][l][m][v][(im,re)] bf16 = sum_k leg[l][m][k]*qw[k]*F
// F now PLANAR [k][c*64+v].  grid (mch, NBTE), block 256: 8 l x 8 cols.
// ---------------------------------------------------------------------------
__global__ __launch_bounds__(256) void leg_contract(const float* __restrict__ F,
                                                    const float* __restrict__ leg,
                                                    const float* __restrict__ qw,
                                                    unsigned short* __restrict__ out,
                                                    int m_base, int mch) {
    __shared__ float As[16 * 128];     // [kk][l]
    __shared__ float Fs[16 * 128];     // [kk][c*64+v] planar (direct copy)
    __shared__ float qs[NLAT];
    const int mi  = blockIdx.x;
    const int m   = m_base + mi;
    const int bte = blockIdx.y;
    const int t   = threadIdx.x;
    qs[t] = qw[t];

    const int cg = t & 15;             // cols: re v=4cg..+3 and im v=4cg..+3
    const int lq = t >> 4;             // l = lq*8 .. +7
    const int la = t >> 1;
    const int kh = (t & 1) * 8;

    const float4* Fb4 = (const float4*)(F + (size_t)(bte * mch + mi) * (NLAT * NV * 2));
    float4* As4 = (float4*)As;
    float4* Fs4 = (float4*)Fs;

    float acc[8][8];
    #pragma unroll
    for (int i = 0; i < 8; ++i)
        #pragma unroll
        for (int j = 0; j < 8; ++j) acc[i][j] = 0.f;

    for (int k0 = 0; k0 < NLAT; k0 += 16) {
        __syncthreads();
        {   // A: As[kk][l] = leg[la][m][k0+kk] * qw[k0+kk]
            const float* lp = leg + ((size_t)la * MMAXX + m) * NLAT + k0 + kh;
            const float4 p0 = *(const float4*)lp;
            const float4 p1 = *(const float4*)(lp + 4);
            const float pv[8] = {p0.x, p0.y, p0.z, p0.w, p1.x, p1.y, p1.z, p1.w};
            #pragma unroll
            for (int j = 0; j < 8; ++j)
                As[(kh + j) * 128 + la] = pv[j] * qs[k0 + kh + j];
        }
        #pragma unroll
        for (int j = 0; j < 2; ++j) {  // F stage: direct (already planar)
            const int g = t + j * 256;
            Fs4[g] = Fb4[k0 * 32 + g];
        }
        __syncthreads();
        #pragma unroll 4
        for (int kk = 0; kk < 16; ++kk) {
            const float4 a0 = As4[kk * 32 + lq * 2];
            const float4 a1 = As4[kk * 32 + lq * 2 + 1];
            const float4 f0 = Fs4[kk * 32 + cg];        // re v=4cg..+3
            const float4 f1 = Fs4[kk * 32 + 16 + cg];   // im v=4cg..+3
            const float av[8] = {a0.x, a0.y, a0.z, a0.w, a1.x, a1.y, a1.z, a1.w};
            const float fv[8] = {f0.x, f0.y, f0.z, f0.w, f1.x, f1.y, f1.z, f1.w};
            #pragma unroll
            for (int i = 0; i < 8; ++i)
                #pragma unroll
                for (int j = 0; j < 8; ++j)
                    acc[i][j] = fmaf(av[i], fv[j], acc[i][j]);
        }
    }

    // acc[i][j]: j=0..3 -> re(v=4cg+j), j=4..7 -> im(v=4cg+j-4). Pair = (im,re).
    #pragma unroll
    for (int i = 0; i < 8; ++i) {
        const int l = lq * 8 + i;
        unsigned short* dp = out + ((size_t)(bte * LMAXX + l) * MMAXX + m) * (NV * 2) + cg * 8;
        uint4 pk;
        pk.x = f2bf(acc[i][4]) | (f2bf(acc[i][0]) << 16);
        pk.y = f2bf(acc[i][5]) | (f2bf(acc[i][1]) << 16);
        pk.z = f2bf(acc[i][6]) | (f2bf(acc[i][2]) << 16);
        pk.w = f2bf(acc[i][7]) | (f2bf(acc[i][3]) << 16);
        *(uint4*)dp = pk;
    }
}

extern "C" void kernel_launch(void* const* d_in, const int* in_sizes, int n_in,
                              void* d_out, int out_size, void* d_ws, size_t ws_size,
                              hipStream_t stream) {
    const float* data = (const float*)d_in[0];    // [4][256][512][64] fp32
    const float* leg  = (const float*)d_in[1];    // [128][128][256] fp32
    const float* qw   = (const float*)d_in[2];    // [256] fp32
    unsigned short* out = (unsigned short*)d_out; // bf16 [4][128][128][64][(im,re)]

    unsigned short* tsw = (unsigned short*)d_ws;              // 256 KB
    float* F = (float*)((char*)d_ws + 131072 * sizeof(unsigned short));

    const size_t per_m = (size_t)NBTE * NLAT * NV * 2 * sizeof(float); // 512 KB
    int mch = MMAXX;
    while (mch > 8 && 262144 + per_m * (size_t)mch > ws_size) mch >>= 1;

    if (mch == MMAXX) {
        init_tsw<<<dim3(512), 256, 0, stream>>>(tsw);
        dft_mfma<<<dim3(NBTE * NLAT / 2), 256, 0, stream>>>(data, tsw, F);
        leg_contract<<<dim3(MMAXX, NBTE), 256, 0, stream>>>(F, leg, qw, out, 0, MMAXX);
    } else {
        const int nch = MMAXX / mch;
        for (int c = 0; c < nch; ++c) {
            const int mb = c * mch;
            if (mch == 64)
                dft_lon<2><<<dim3(NBTE * NLAT), 256, 0, stream>>>(data, F, mb, mch);
            else
                dft_lon<1><<<dim3(NBTE * NLAT), 256, 0, stream>>>(data, F, mb, mch);
            leg_contract<<<dim3(mch, NBTE), 256, 0, stream>>>(F, leg, qw, out, mb, mch);
        }
    }
}

// Round 12
// 109.942 us; speedup vs baseline: 33.8959x; 1.4505x over previous
//
#include <hip/hip_runtime.h>

#define NLAT  256
#define NLON  512
#define LMAXX 128
#define MMAXX 128
#define NV    64
#define NBTE  4   // B*T*E = 2*2*1

typedef __attribute__((ext_vector_type(8))) short bf16x8;
typedef __attribute__((ext_vector_type(4))) short bf16x4;
typedef __attribute__((ext_vector_type(4))) float f32x4;

// round-to-nearest-even float -> bf16
__device__ __forceinline__ unsigned int f2bf(float x) {
    union { float f; unsigned int u; } a; a.f = x;
    return (a.u + 0x7fffu + ((a.u >> 16) & 1u)) >> 16;
}

// ---------------------------------------------------------------------------
// init_tsw: twiddle matrix T[256][512] bf16, pre-swizzled into MFMA A-fragment
// order.  T[row][n]: row<128 -> cos(2*pi*row*n/512) (re), row>=128 -> -sin (im).
// Flat: tsw[((ks*16 + mt)*64 + l)*8 + i] = T[mt*16+(l&15)][ks*32+(l>>4)*8+i]
// ---------------------------------------------------------------------------
__global__ __launch_bounds__(256) void init_tsw(unsigned short* __restrict__ tsw) {
    const int gid = blockIdx.x * 256 + threadIdx.x;   // 131072 total
    const int i  = gid & 7;
    const int l  = (gid >> 3) & 63;
    const int mt = (gid >> 9) & 15;
    const int ks = gid >> 13;
    const int row = mt * 16 + (l & 15);
    const int n   = ks * 32 + (l >> 4) * 8 + i;
    const int m   = row & 127;
    float s, c;
    sincosf((6.28318530717958647692f / NLON) * (float)((m * n) & (NLON - 1)), &s, &c);
    const float val = (row < 128) ? c : -s;
    tsw[gid] = (unsigned short)f2bf(val);
}

// ---------------------------------------------------------------------------
// dft_mfma v2: one lat-row per block (grid 1024), 4 waves = (m-half, v-half).
// Wave: 8 mt (128 M-rows = its re/im half) x 2 vt (32 v). acc = 64 VGPR.
// F[bte][m][lat][cpl*64+v] planar fp32.
// ---------------------------------------------------------------------------
__global__ __launch_bounds__(256, 3) void dft_mfma(const float* __restrict__ data,
                                                   const unsigned short* __restrict__ tsw,
                                                   float* __restrict__ F) {
    __shared__ unsigned short xs[64][136];   // [v][n] bf16, 17.4 KB
    const int t  = threadIdx.x;
    const int l  = t & 63;
    const int q  = t >> 6;             // wave
    const int mh = q >> 1;             // m half: 0 = re-rows, 1 = im-rows
    const int vh = q & 1;              // v half
    const int row = blockIdx.x;        // bte*NLAT + lat

    f32x4 acc[8][2];
    #pragma unroll
    for (int mt = 0; mt < 8; ++mt)
        #pragma unroll
        for (int vt = 0; vt < 2; ++vt) acc[mt][vt] = (f32x4){0.f, 0.f, 0.f, 0.f};

    const int vv = t & 63;             // staging: v (lane -> coalesced)
    const int ng = t >> 6;             // staging: n subgroup (32 n each)

    for (int ch = 0; ch < 4; ++ch) {   // 128-n chunks
        __syncthreads();
        {   // stage X: fp32 -> bf16, transposed to [v][n]
            const float* Xp = data + ((size_t)row * NLON + ch * 128 + ng * 32) * NV + vv;
            #pragma unroll
            for (int g = 0; g < 8; ++g) {
                bf16x4 pk;
                pk.x = (short)f2bf(Xp[(g * 4 + 0) * NV]);
                pk.y = (short)f2bf(Xp[(g * 4 + 1) * NV]);
                pk.z = (short)f2bf(Xp[(g * 4 + 2) * NV]);
                pk.w = (short)f2bf(Xp[(g * 4 + 3) * NV]);
                *(bf16x4*)&xs[vv][ng * 32 + g * 4] = pk;
            }
        }
        __syncthreads();
        #pragma unroll
        for (int ks = 0; ks < 4; ++ks) {   // k32 steps
            const bf16x8 b0 = *(const bf16x8*)&xs[vh * 32 + (l & 15)][ks * 32 + (l >> 4) * 8];
            const bf16x8 b1 = *(const bf16x8*)&xs[vh * 32 + 16 + (l & 15)][ks * 32 + (l >> 4) * 8];
            const unsigned short* ap = tsw + ((size_t)((ch * 4 + ks) * 16 + mh * 8)) * 512 + l * 8;
            #pragma unroll
            for (int mt = 0; mt < 8; ++mt) {
                const bf16x8 a = *(const bf16x8*)(ap + mt * 512);
                acc[mt][0] = __builtin_amdgcn_mfma_f32_16x16x32_bf16(a, b0, acc[mt][0], 0, 0, 0);
                acc[mt][1] = __builtin_amdgcn_mfma_f32_16x16x32_bf16(a, b1, acc[mt][1], 0, 0, 0);
            }
        }
    }

    // epilogue: D[row = (mh*8+mt)*16 + (l>>4)*4 + j][col = vh*32+vt*16+(l&15)]
    const int bte = row >> 8, lat = row & (NLAT - 1);
    const int g4    = (l >> 4) * 4;
    const int vbase = vh * 32 + (l & 15);
    #pragma unroll
    for (int mt = 0; mt < 8; ++mt) {
        #pragma unroll
        for (int j = 0; j < 4; ++j) {
            const int m = mt * 16 + g4 + j;          // (mh*128 + m) & 127 == m
            float* dp = F + ((size_t)(bte * MMAXX + m) * NLAT + lat) * (NV * 2) + mh * 64 + vbase;
            dp[0]  = acc[mt][0][j];
            dp[16] = acc[mt][1][j];
        }
    }
}

// ---------------------------------------------------------------------------
// Fallback fp32 DFT (only if ws too small for full-m F) — planar F epilogue.
// ---------------------------------------------------------------------------
template<int MPT>
__global__ __launch_bounds__(256) void dft_lon(const float* __restrict__ data,
                                               float* __restrict__ F,
                                               int m_base, int mch) {
    __shared__ float2 tw[NLON];
    __shared__ float  xs[64 * NV];
    const int row = blockIdx.x;
    const int t   = threadIdx.x;
    const float* __restrict__ X = data + (size_t)row * (NLON * NV);

    for (int i = t; i < NLON; i += 256) {
        float s, c;
        sincosf((6.28318530717958647692f / NLON) * (float)i, &s, &c);
        tw[i] = make_float2(c, -s);
    }
    const int mg = t >> 3, vg = t & 7;
    const int m0 = m_base + mg * MPT;

    float ar[MPT][8], ai[MPT][8];
    #pragma unroll
    for (int j = 0; j < MPT; ++j)
        #pragma unroll
        for (int v = 0; v < 8; ++v) { ar[j][v] = 0.f; ai[j][v] = 0.f; }
    int idx[MPT];
    #pragma unroll
    for (int j = 0; j < MPT; ++j) idx[j] = 0;

    for (int chunk = 0; chunk < NLON / 64; ++chunk) {
        __syncthreads();
        const float4* src = (const float4*)(X + (size_t)chunk * 64 * NV);
        float4*       dst = (float4*)xs;
        #pragma unroll
        for (int j = 0; j < 4; ++j) dst[t + j * 256] = src[t + j * 256];
        __syncthreads();
        for (int n = 0; n < 64; ++n) {
            const float4 x0 = *(const float4*)&xs[n * NV + vg * 8];
            const float4 x1 = *(const float4*)&xs[n * NV + vg * 8 + 4];
            const float xv[8] = {x0.x, x0.y, x0.z, x0.w, x1.x, x1.y, x1.z, x1.w};
            #pragma unroll
            for (int j = 0; j < MPT; ++j) {
                const float2 w = tw[idx[j]];
                idx[j] = (idx[j] + m0 + j) & (NLON - 1);
                #pragma unroll
                for (int v = 0; v < 8; ++v) {
                    ar[j][v] = fmaf(w.x, xv[v], ar[j][v]);
                    ai[j][v] = fmaf(w.y, xv[v], ai[j][v]);
                }
            }
        }
    }
    const int bte = row >> 8, lat = row & (NLAT - 1);
    #pragma unroll
    for (int j = 0; j < MPT; ++j) {
        const int mi = mg * MPT + j;
        if (mi < mch) {
            float* dp = F + ((size_t)(bte * mch + mi) * NLAT + lat) * (NV * 2);
            *(float4*)(dp + vg * 8)          = make_float4(ar[j][0], ar[j][1], ar[j][2], ar[j][3]);
            *(float4*)(dp + vg * 8 + 4)      = make_float4(ar[j][4], ar[j][5], ar[j][6], ar[j][7]);
            *(float4*)(dp + 64 + vg * 8)     = make_float4(ai[j][0], ai[j][1], ai[j][2], ai[j][3]);
            *(float4*)(dp + 64 + vg * 8 + 4) = make_float4(ai[j][4], ai[j][5], ai[j][6], ai[j][7]);
        }
    }
}

// ---------------------------------------------------------------------------
// leg_contract: out[bte][l][m][v][(im,re)] bf16 = sum_k leg[l][m][k]*qw[k]*F
// F PLANAR [k][c*64+v].  grid (mch, NBTE), block 256: 8 l x 8 cols.
// ---------------------------------------------------------------------------
__global__ __launch_bounds__(256) void leg_contract(const float* __restrict__ F,
                                                    const float* __restrict__ leg,
                                                    const float* __restrict__ qw,
                                                    unsigned short* __restrict__ out,
                                                    int m_base, int mch) {
    __shared__ float As[16 * 128];     // [kk][l]
    __shared__ float Fs[16 * 128];     // [kk][c*64+v] planar (direct copy)
    __shared__ float qs[NLAT];
    const int mi  = blockIdx.x;
    const int m   = m_base + mi;
    const int bte = blockIdx.y;
    const int t   = threadIdx.x;
    qs[t] = qw[t];

    const int cg = t & 15;             // cols: re v=4cg..+3 and im v=4cg..+3
    const int lq = t >> 4;             // l = lq*8 .. +7
    const int la = t >> 1;
    const int kh = (t & 1) * 8;

    const float4* Fb4 = (const float4*)(F + (size_t)(bte * mch + mi) * (NLAT * NV * 2));
    float4* As4 = (float4*)As;
    float4* Fs4 = (float4*)Fs;

    float acc[8][8];
    #pragma unroll
    for (int i = 0; i < 8; ++i)
        #pragma unroll
        for (int j = 0; j < 8; ++j) acc[i][j] = 0.f;

    for (int k0 = 0; k0 < NLAT; k0 += 16) {
        __syncthreads();
        {   // A: As[kk][l] = leg[la][m][k0+kk] * qw[k0+kk]
            const float* lp = leg + ((size_t)la * MMAXX + m) * NLAT + k0 + kh;
            const float4 p0 = *(const float4*)lp;
            const float4 p1 = *(const float4*)(lp + 4);
            const float pv[8] = {p0.x, p0.y, p0.z, p0.w, p1.x, p1.y, p1.z, p1.w};
            #pragma unroll
            for (int j = 0; j < 8; ++j)
                As[(kh + j) * 128 + la] = pv[j] * qs[k0 + kh + j];
        }
        #pragma unroll
        for (int j = 0; j < 2; ++j) {  // F stage: direct (already planar)
            const int g = t + j * 256;
            Fs4[g] = Fb4[k0 * 32 + g];
        }
        __syncthreads();
        #pragma unroll 4
        for (int kk = 0; kk < 16; ++kk) {
            const float4 a0 = As4[kk * 32 + lq * 2];
            const float4 a1 = As4[kk * 32 + lq * 2 + 1];
            const float4 f0 = Fs4[kk * 32 + cg];        // re v=4cg..+3
            const float4 f1 = Fs4[kk * 32 + 16 + cg];   // im v=4cg..+3
            const float av[8] = {a0.x, a0.y, a0.z, a0.w, a1.x, a1.y, a1.z, a1.w};
            const float fv[8] = {f0.x, f0.y, f0.z, f0.w, f1.x, f1.y, f1.z, f1.w};
            #pragma unroll
            for (int i = 0; i < 8; ++i)
                #pragma unroll
                for (int j = 0; j < 8; ++j)
                    acc[i][j] = fmaf(av[i], fv[j], acc[i][j]);
        }
    }

    // acc[i][j]: j=0..3 -> re(v=4cg+j), j=4..7 -> im(v=4cg+j-4). Pair = (im,re).
    #pragma unroll
    for (int i = 0; i < 8; ++i) {
        const int l = lq * 8 + i;
        unsigned short* dp = out + ((size_t)(bte * LMAXX + l) * MMAXX + m) * (NV * 2) + cg * 8;
        uint4 pk;
        pk.x = f2bf(acc[i][4]) | (f2bf(acc[i][0]) << 16);
        pk.y = f2bf(acc[i][5]) | (f2bf(acc[i][1]) << 16);
        pk.z = f2bf(acc[i][6]) | (f2bf(acc[i][2]) << 16);
        pk.w = f2bf(acc[i][7]) | (f2bf(acc[i][3]) << 16);
        *(uint4*)dp = pk;
    }
}

extern "C" void kernel_launch(void* const* d_in, const int* in_sizes, int n_in,
                              void* d_out, int out_size, void* d_ws, size_t ws_size,
                              hipStream_t stream) {
    const float* data = (const float*)d_in[0];    // [4][256][512][64] fp32
    const float* leg  = (const float*)d_in[1];    // [128][128][256] fp32
    const float* qw   = (const float*)d_in[2];    // [256] fp32
    unsigned short* out = (unsigned short*)d_out; // bf16 [4][128][128][64][(im,re)]

    unsigned short* tsw = (unsigned short*)d_ws;              // 256 KB
    float* F = (float*)((char*)d_ws + 131072 * sizeof(unsigned short));

    const size_t per_m = (size_t)NBTE * NLAT * NV * 2 * sizeof(float); // 512 KB
    int mch = MMAXX;
    while (mch > 8 && 262144 + per_m * (size_t)mch > ws_size) mch >>= 1;

    if (mch == MMAXX) {
        init_tsw<<<dim3(512), 256, 0, stream>>>(tsw);
        dft_mfma<<<dim3(NBTE * NLAT), 256, 0, stream>>>(data, tsw, F);
        leg_contract<<<dim3(MMAXX, NBTE), 256, 0, stream>>>(F, leg, qw, out, 0, MMAXX);
    } else {
        const int nch = MMAXX / mch;
        for (int c = 0; c < nch; ++c) {
            const int mb = c * mch;
            if (mch == 64)
                dft_lon<2><<<dim3(NBTE * NLAT), 256, 0, stream>>>(data, F, mb, mch);
            else
                dft_lon<1><<<dim3(NBTE * NLAT), 256, 0, stream>>>(data, F, mb, mch);
            leg_contract<<<dim3(mch, NBTE), 256, 0, stream>>>(F, leg, qw, out, mb, mch);
        }
    }
}